// Round 1
// 645.341 us; speedup vs baseline: 1.0079x; 1.0079x over previous
//
#include <hip/hip_runtime.h>

// LSALayer fused: windowed (4x4 patch, 16-token) self-attention, C=256.
// Register-resident dataflow, ZERO LDS, zero barriers.
//
// Key idea: swap GEMM1 operands -> Q lands transposed in registers:
//   lane (l15,quad), tile nt, reg r  holds  Q[token=l15][c = nt*16 + quad*4 + r]
// which is exactly the A/B fragment layout of v_mfma_f32_16x16x16_bf16.
//  - S = Q Q^T straight from regs (S bitwise symmetric -> softmax reduces
//    over quads via shfl_xor(16/32); P is born in A-frag layout).
//  - out = (P Q) Wo^T  ==  P (Q Wo^T):  Y = Q Wo^T uses reg-Q as B-operand;
//    per 16-ch tile Y is transposed with one identity-MFMA, then one MFMA
//    with P produces the output tile.

typedef __attribute__((ext_vector_type(8))) short short8;   // 8 bf16
typedef __attribute__((ext_vector_type(4))) short short4v;  // 4 bf16
typedef __attribute__((ext_vector_type(4))) float floatx4;  // MFMA C/D

#define MFMA32(a, b, c) __builtin_amdgcn_mfma_f32_16x16x32_bf16(a, b, c, 0, 0, 0)
#define MFMA16(a, b, c) __builtin_amdgcn_mfma_f32_16x16x16bf16_1k(a, b, c, 0, 0, 0)

static __device__ inline short f2bf(float f) {
    unsigned u = __float_as_uint(f);
    u = (u + 0x7FFFu + ((u >> 16) & 1u)) >> 16;  // RNE
    return (short)u;
}
static __device__ inline floatx4 zf4() {
    floatx4 v;
#pragma unroll
    for (int k = 0; k < 4; ++k) v[k] = 0.0f;
    return v;
}
static __device__ inline short8 cvt8(float4 v0, float4 v1) {
    short8 a;
    a[0] = f2bf(v0.x); a[1] = f2bf(v0.y); a[2] = f2bf(v0.z); a[3] = f2bf(v0.w);
    a[4] = f2bf(v1.x); a[5] = f2bf(v1.y); a[6] = f2bf(v1.z); a[7] = f2bf(v1.w);
    return a;
}
static __device__ inline short4v pack4(floatx4 a) {
    short4v r;
    r[0] = f2bf(a[0]); r[1] = f2bf(a[1]); r[2] = f2bf(a[2]); r[3] = f2bf(a[3]);
    return r;
}
static __device__ inline short4v pack4b(floatx4 a, float4 b) {
    short4v r;
    r[0] = f2bf(a[0] + b.x); r[1] = f2bf(a[1] + b.y);
    r[2] = f2bf(a[2] + b.z); r[3] = f2bf(a[3] + b.w);
    return r;
}

// Wq: row-major bf16 (GEMM1 A-frag does 16B loads of 8 contiguous k).
// Wo: permuted so one 16B load serves TWO K=16 fragments:
//   src k = kk*16 + q4*4 + r  ->  dst = (kk>>1)*32 + q4*8 + (kk&1)*4 + r
__global__ void convert_weights(const float* __restrict__ Wq,
                                const float* __restrict__ Wo,
                                short* __restrict__ wbf) {
    int idx = blockIdx.x * 256 + threadIdx.x;  // 0..65535
    int n = idx >> 8, k = idx & 255;
    wbf[idx] = f2bf(Wq[idx]);
    int kk = k >> 4, q4 = (k >> 2) & 3, r = k & 3;
    int pk = (kk >> 1) * 32 + q4 * 8 + (kk & 1) * 4 + r;
    wbf[65536 + n * 256 + pk] = f2bf(Wo[idx]);
}

// Block = 256 threads = 4 waves; each wave owns TWO windows (shared W-frags).
// Grid = 2048 blocks -> 16384 windows. No LDS, no barriers.
__global__ __launch_bounds__(256, 3) void lsa_fused(
    const float* __restrict__ x, const short* __restrict__ wbf,
    const float* __restrict__ bq, const float* __restrict__ bo,
    float* __restrict__ out) {
    const int tid  = threadIdx.x;
    const int wv   = tid >> 6;
    const int lane = tid & 63;
    const int l15  = lane & 15;
    const int quad = lane >> 4;

    const int wid0 = (blockIdx.x * 4 + wv) * 2;
    const int pi = l15 >> 2, pj = l15 & 3;  // token l15 -> pixel in 4x4 patch

    const float* xrow[2];
#pragma unroll
    for (int w = 0; w < 2; ++w) {
        int wid = wid0 + w;
        int b = wid >> 12, hp = (wid >> 6) & 63, wp = wid & 63;
        xrow[w] = x + ((size_t)b << 24) + ((size_t)((hp << 2) + pi) << 16)
                    + ((size_t)((wp << 2) + pj) << 8);
    }

    // ---- stage X (HBM) into bf16 B-frags: lane holds X[l15][kk*32+quad*8 ..+8]
    short8 xf[2][8];
#pragma unroll
    for (int w = 0; w < 2; ++w)
#pragma unroll
        for (int kk = 0; kk < 8; ++kk) {
            const float* p = xrow[w] + kk * 32 + quad * 8;
            float4 v0 = *(const float4*)p;
            float4 v1 = *(const float4*)(p + 4);
            xf[w][kk] = cvt8(v0, v1);
        }

    // ---- GEMM1 (swapped): acc = mfma(Wq_frag, X_frag) -> Q transposed in regs.
    // qf[w][nt][r] = bf16( Q[token l15][nt*16 + quad*4 + r] + bq )
    short4v qf[2][16];
#pragma unroll 2
    for (int nt = 0; nt < 16; ++nt) {
        floatx4 a0 = zf4(), a1 = zf4();
        const short* wq = wbf + (nt * 16 + l15) * 256 + quad * 8;
#pragma unroll
        for (int kk = 0; kk < 8; ++kk) {
            short8 wf = *(const short8*)(wq + kk * 32);
            a0 = MFMA32(wf, xf[0][kk], a0);
            a1 = MFMA32(wf, xf[1][kk], a1);
        }
        float4 b4 = *(const float4*)(bq + nt * 16 + quad * 4);
        qf[0][nt] = pack4b(a0, b4);
        qf[1][nt] = pack4b(a1, b4);
    }

    // ---- S = Q Q^T from registers (16x16x16, A==B). s[r] = S[quad*4+r][l15]
    //      = (symmetry) S[l15][quad*4+r]: row l15 is spread over (quad, r).
    floatx4 s0 = zf4(), s1 = zf4();
#pragma unroll
    for (int nt = 0; nt < 16; ++nt) {
        s0 = MFMA16(qf[0][nt], qf[0][nt], s0);
        s1 = MFMA16(qf[1][nt], qf[1][nt], s1);
    }

    // ---- softmax over row l15: reduce in-lane over r, then across quads.
    // Result paf[r] = P[l15][quad*4+r]  == A-frag layout for the PY mfma.
    short4v paf[2];
#pragma unroll
    for (int w = 0; w < 2; ++w) {
        floatx4 s = w ? s1 : s0;
        float m = fmaxf(fmaxf(s[0], s[1]), fmaxf(s[2], s[3]));
        m = fmaxf(m, __shfl_xor(m, 16, 64));
        m = fmaxf(m, __shfl_xor(m, 32, 64));
        float e0 = __expf(s[0] - m), e1 = __expf(s[1] - m);
        float e2 = __expf(s[2] - m), e3 = __expf(s[3] - m);
        float sum = (e0 + e1) + (e2 + e3);
        sum += __shfl_xor(sum, 16, 64);
        sum += __shfl_xor(sum, 32, 64);
        float inv = 1.0f / sum;
        short4v pf;
        pf[0] = f2bf(e0 * inv); pf[1] = f2bf(e1 * inv);
        pf[2] = f2bf(e2 * inv); pf[3] = f2bf(e3 * inv);
        paf[w] = pf;
    }

    // identity B-frag (bf16 1.0 = 0x3F80) for the in-register transpose mfma
    short4v idf;
#pragma unroll
    for (int j = 0; j < 4; ++j) idf[j] = (l15 == quad * 4 + j) ? (short)0x3F80 : (short)0;

    float* o0p = out + (size_t)wid0 * 4096;
    float* o1p = o0p + 4096;

    // ---- per 16-ch tile: Y = Q Wo^T (reg-Q as B), transpose Y via identity
    //      mfma, out_tile = P * Y^T-frag, add bo, store.
#pragma unroll 2
    for (int nt = 0; nt < 16; ++nt) {
        floatx4 y0 = zf4(), y1 = zf4();
        const short* wo = wbf + 65536 + (nt * 16 + l15) * 256 + quad * 8;
#pragma unroll
        for (int kk2 = 0; kk2 < 8; ++kk2) {
            short8 wf = *(const short8*)(wo + kk2 * 32);
            short4v wlo, whi;
            wlo[0] = wf[0]; wlo[1] = wf[1]; wlo[2] = wf[2]; wlo[3] = wf[3];
            whi[0] = wf[4]; whi[1] = wf[5]; whi[2] = wf[6]; whi[3] = wf[7];
            y0 = MFMA16(wlo, qf[0][2 * kk2], y0);
            y1 = MFMA16(wlo, qf[1][2 * kk2], y1);
            y0 = MFMA16(whi, qf[0][2 * kk2 + 1], y0);
            y1 = MFMA16(whi, qf[1][2 * kk2 + 1], y1);
        }
        // y[r] = Y[token l15][nt*16+quad*4+r]  --(identity mfma)-->
        // t[r] = Y[token quad*4+r][nt*16+l15]  (B-frag layout for PY)
        floatx4 t0 = MFMA16(pack4(y0), idf, zf4());
        floatx4 t1 = MFMA16(pack4(y1), idf, zf4());
        floatx4 o0 = MFMA16(paf[0], pack4(t0), zf4());
        floatx4 o1 = MFMA16(paf[1], pack4(t1), zf4());
        float bov = bo[nt * 16 + l15];
#pragma unroll
        for (int r = 0; r < 4; ++r) {
            o0p[(quad * 4 + r) * 256 + nt * 16 + l15] = o0[r] + bov;
            o1p[(quad * 4 + r) * 256 + nt * 16 + l15] = o1[r] + bov;
        }
    }
}

extern "C" void kernel_launch(void* const* d_in, const int* in_sizes, int n_in,
                              void* d_out, int out_size, void* d_ws, size_t ws_size,
                              hipStream_t stream) {
    const float* x  = (const float*)d_in[0];
    const float* Wq = (const float*)d_in[1];
    const float* bq = (const float*)d_in[2];
    const float* Wo = (const float*)d_in[3];
    const float* bo = (const float*)d_in[4];
    float* out = (float*)d_out;
    short* wbf = (short*)d_ws;  // [0,65536): Wq bf16; [65536,131072): Wo bf16 (permuted)

    hipLaunchKernelGGL(convert_weights, dim3(256), dim3(256), 0, stream, Wq, Wo, wbf);
    hipLaunchKernelGGL(lsa_fused, dim3(2048), dim3(256), 0, stream,
                       x, wbf, bq, bo, out);
}